// Round 5
// baseline (29805.206 us; speedup 1.0000x reference)
//
#include <hip/hip_runtime.h>

// Reservoir forward, R5: single-XCD sync domain.
//   32 participant wgs (selected to share XCD 0 via HW_REG_XCC_ID + delayed-claim
//   fallback) exchange epoch-tagged state through their XCD's own L2 instead of
//   the cross-XCD fabric. W: 48 rows/wg in VGPRs (96 regs/thr) + 16 rows/wg in LDS.

typedef unsigned long long u64;

#define NRES 2048
#define NIN  64
#define NOUT 16
#define TT   4096
#define NLAUNCH 256        // launched wgs (1 per CU)
#define NPART 32           // participants (one XCD's worth of CUs)
#define BTH  1024          // threads per wg (16 waves)
#define ROWS_PER_WG 64     // NRES / NPART
#define NJ 8               // float4 blocks per row-slice (32 cols/lane)

__global__ void init_ws(u64* statebuf, unsigned* claim) {
    int i = blockIdx.x * blockDim.x + threadIdx.x;
    if (i < NRES)            statebuf[i] = 0ull;                   // buf0: epoch 0, value 0
    else if (i < 2 * NRES)   statebuf[i] = 0xFFFFFFFF00000000ull;  // buf1: invalid epoch
    if (i == 0) claim[0] = 0u;
}

__launch_bounds__(BTH, 4)
__global__ void reservoir_run(const float* __restrict__ inputs,
                              const float* __restrict__ outputs,
                              const float* __restrict__ noise,
                              const float* __restrict__ w,
                              const float* __restrict__ w_in,
                              const float* __restrict__ w_feedb,
                              u64* statebuf, unsigned* claim)
{
    __shared__ unsigned s_slot;
    __shared__ float s_state[2][NRES];    // 16 KB, parity double buffer
    __shared__ float w_lds[16][NRES];     // 128 KB: each wave's 4th row

    // XCD id (hwreg 20 = HW_REG_XCC_ID, verified on MI355X). Non-XCD0 wgs delay
    // their claim ~54us so XCD0 wgs win the 32 slots; fallback keeps it deadlock-free.
    unsigned xcc;
    asm volatile("s_getreg_b32 %0, hwreg(20, 0, 32)" : "=s"(xcc));
    if ((xcc & 7u) != 0u) {
        for (int i = 0; i < 16; ++i) __builtin_amdgcn_s_sleep(127);
    }
    if (threadIdx.x == 0)
        s_slot = __hip_atomic_fetch_add(claim, 1u, __ATOMIC_RELAXED,
                                        __HIP_MEMORY_SCOPE_AGENT);
    __syncthreads();
    const unsigned slot = s_slot;
    if (slot >= NPART) return;            // uniform per-wg exit

    const int tid  = threadIdx.x;
    const int wave = tid >> 6;            // 0..15
    const int lane = tid & 63;
    const int row0 = (int)slot * ROWS_PER_WG + wave * 4;   // wave owns rows row0..row0+3

    // ---- W rows 0..2 into VGPRs (float4 x 8 = 32 cols/lane each) ----
    const float4* wr0 = (const float4*)(w + (size_t)(row0 + 0) * NRES);
    const float4* wr1 = (const float4*)(w + (size_t)(row0 + 1) * NRES);
    const float4* wr2 = (const float4*)(w + (size_t)(row0 + 2) * NRES);
    const float4* wr3 = (const float4*)(w + (size_t)(row0 + 3) * NRES);
    float4 wv0[NJ], wv1[NJ], wv2[NJ];
#pragma unroll
    for (int j = 0; j < NJ; ++j) {
        wv0[j] = wr0[64 * j + lane];
        wv1[j] = wr1[64 * j + lane];
        wv2[j] = wr2[64 * j + lane];
    }
    // pin: block rematerialization (R3's failure mode)
#pragma unroll
    for (int j = 0; j < NJ; ++j) {
        asm volatile("" : "+v"(wv0[j].x), "+v"(wv0[j].y), "+v"(wv0[j].z), "+v"(wv0[j].w));
        asm volatile("" : "+v"(wv1[j].x), "+v"(wv1[j].y), "+v"(wv1[j].z), "+v"(wv1[j].w));
        asm volatile("" : "+v"(wv2[j].x), "+v"(wv2[j].y), "+v"(wv2[j].z), "+v"(wv2[j].w));
    }
    // ---- W row 3 into this wave's private LDS row ----
    {
        float4* wl = (float4*)&w_lds[wave][0];
#pragma unroll
        for (int j = 0; j < NJ; ++j) wl[64 * j + lane] = wr3[64 * j + lane];
    }

    const float wi0 = w_in[(row0 + 0) * NIN + lane];
    const float wi1 = w_in[(row0 + 1) * NIN + lane];
    const float wi2 = w_in[(row0 + 2) * NIN + lane];
    const float wi3 = w_in[(row0 + 3) * NIN + lane];
    const float wf0 = (lane < NOUT) ? w_feedb[(row0 + 0) * NOUT + lane] : 0.0f;
    const float wf1 = (lane < NOUT) ? w_feedb[(row0 + 1) * NOUT + lane] : 0.0f;
    const float wf2 = (lane < NOUT) ? w_feedb[(row0 + 2) * NOUT + lane] : 0.0f;
    const float wf3 = (lane < NOUT) ? w_feedb[(row0 + 3) * NOUT + lane] : 0.0f;

    // software-pipelined externals (HBM latency hides under previous step's compute)
    float inp_c = inputs[1 * NIN + lane];
    float po_c  = (lane < NOUT) ? outputs[0 * NOUT + lane] : 0.0f;
    float nz_c  = (lane < 4) ? noise[(size_t)1 * NRES + row0 + lane] : 0.0f;

    for (int t = 1; t < TT; ++t) {
        const u64* sbuf = statebuf + ((t - 1) & 1) * NRES;
        u64*       dbuf = statebuf + (t & 1) * NRES;
        float*     sl   = s_state[(t - 1) & 1];
        const unsigned want = (unsigned)(t - 1);

        float a0 = fmaf(wf0, po_c, wi0 * inp_c);
        float a1 = fmaf(wf1, po_c, wi1 * inp_c);
        float a2 = fmaf(wf2, po_c, wi2 * inp_c);
        float a3 = fmaf(wf3, po_c, wi3 * inp_c);
        const float nz = nz_c;

        // ---- poll-stage state(t-1): epoch tag IS the sync; both loads in flight ----
        u64 p0 = __hip_atomic_load(&sbuf[tid],       __ATOMIC_RELAXED, __HIP_MEMORY_SCOPE_AGENT);
        u64 p1 = __hip_atomic_load(&sbuf[tid + BTH], __ATOMIC_RELAXED, __HIP_MEMORY_SCOPE_AGENT);
        while ((unsigned)(p0 >> 32) != want)
            p0 = __hip_atomic_load(&sbuf[tid], __ATOMIC_RELAXED, __HIP_MEMORY_SCOPE_AGENT);
        while ((unsigned)(p1 >> 32) != want)
            p1 = __hip_atomic_load(&sbuf[tid + BTH], __ATOMIC_RELAXED, __HIP_MEMORY_SCOPE_AGENT);
        sl[tid]       = __uint_as_float((unsigned)p0);
        sl[tid + BTH] = __uint_as_float((unsigned)p1);
        __syncthreads();

        // prefetch next step's externals (arrive during the FMA phase)
        if (t + 1 < TT) {
            inp_c = inputs[(t + 1) * NIN + lane];
            po_c  = (lane < NOUT) ? outputs[t * NOUT + lane] : 0.0f;
            nz_c  = (lane < 4) ? noise[(size_t)(t + 1) * NRES + row0 + lane] : 0.0f;
        }

        // ---- 4 row dot-products: 3 VGPR rows + 1 LDS row, float4 LDS reads ----
        const float4* s4  = (const float4*)sl;
        const float4* wl3 = (const float4*)&w_lds[wave][0];
#pragma unroll
        for (int j = 0; j < NJ; ++j) {
            float4 sv  = s4[64 * j + lane];
            float4 w3v = wl3[64 * j + lane];
            a0 = fmaf(wv0[j].x, sv.x, a0); a0 = fmaf(wv0[j].y, sv.y, a0);
            a0 = fmaf(wv0[j].z, sv.z, a0); a0 = fmaf(wv0[j].w, sv.w, a0);
            a1 = fmaf(wv1[j].x, sv.x, a1); a1 = fmaf(wv1[j].y, sv.y, a1);
            a1 = fmaf(wv1[j].z, sv.z, a1); a1 = fmaf(wv1[j].w, sv.w, a1);
            a2 = fmaf(wv2[j].x, sv.x, a2); a2 = fmaf(wv2[j].y, sv.y, a2);
            a2 = fmaf(wv2[j].z, sv.z, a2); a2 = fmaf(wv2[j].w, sv.w, a2);
            a3 = fmaf(w3v.x,    sv.x, a3); a3 = fmaf(w3v.y,    sv.y, a3);
            a3 = fmaf(w3v.z,    sv.z, a3); a3 = fmaf(w3v.w,    sv.w, a3);
        }
#pragma unroll
        for (int off = 32; off; off >>= 1) {
            a0 += __shfl_xor(a0, off, 64);
            a1 += __shfl_xor(a1, off, 64);
            a2 += __shfl_xor(a2, off, 64);
            a3 += __shfl_xor(a3, off, 64);
        }

        // ---- publish: epoch-tagged u64 stores, 4 rows per wave ----
        if (lane < 4) {
            float a  = (lane == 0) ? a0 : (lane == 1) ? a1 : (lane == 2) ? a2 : a3;
            float ns = tanhf(a) + nz;
            u64 pk = ((u64)(unsigned)t << 32) | (u64)__float_as_uint(ns);
            __hip_atomic_store(&dbuf[row0 + lane], pk, __ATOMIC_RELAXED,
                               __HIP_MEMORY_SCOPE_AGENT);
        }
    }
}

__global__ void epilogue(const u64* __restrict__ statebuf,
                         const float* __restrict__ inputs,
                         const float* __restrict__ outputs,
                         const float* __restrict__ w_out,
                         float* __restrict__ out)
{
    const u64* sb = statebuf + ((TT - 1) & 1) * NRES;   // state(4095) in buf 1
    const int tid  = threadIdx.x;   // 1024 threads = 16 waves
    const int wave = tid >> 6;
    const int lane = tid & 63;

    float acc = 0.0f;
#pragma unroll
    for (int k = 0; k < NRES / 64; ++k) {
        int r = lane + 64 * k;
        acc = fmaf(__uint_as_float((unsigned)sb[r]), w_out[r * NOUT + wave], acc);
    }
#pragma unroll
    for (int off = 32; off; off >>= 1) acc += __shfl_xor(acc, off, 64);
    if (lane == 0) out[wave] = acc;

    for (int i = tid; i < NRES; i += 1024)
        out[NOUT + i] = __uint_as_float((unsigned)sb[i]);
    if (tid < NIN)  out[NOUT + NRES + tid]       = inputs[(TT - 1) * NIN + tid];
    if (tid < NOUT) out[NOUT + NRES + NIN + tid] = outputs[(TT - 2) * NOUT + tid];
}

extern "C" void kernel_launch(void* const* d_in, const int* in_sizes, int n_in,
                              void* d_out, int out_size, void* d_ws, size_t ws_size,
                              hipStream_t stream) {
    const float* inputs  = (const float*)d_in[0];   // (4096, 64)
    const float* outputs = (const float*)d_in[1];   // (4096, 16)
    const float* noise   = (const float*)d_in[2];   // (4096, 2048)
    const float* w       = (const float*)d_in[3];   // (2048, 2048)
    const float* w_in    = (const float*)d_in[4];   // (2048, 64)
    const float* w_feedb = (const float*)d_in[5];   // (2048, 16)
    const float* w_out   = (const float*)d_in[6];   // (2048, 16)
    float* out = (float*)d_out;                     // 16 + 2128 floats

    u64*      statebuf = (u64*)d_ws;                               // 2*2048 u64 = 32 KB
    unsigned* claim    = (unsigned*)((char*)d_ws + 2 * NRES * sizeof(u64));

    init_ws<<<dim3(8), dim3(512), 0, stream>>>(statebuf, claim);
    reservoir_run<<<dim3(NLAUNCH), dim3(BTH), 0, stream>>>(inputs, outputs, noise,
                                                           w, w_in, w_feedb,
                                                           statebuf, claim);
    epilogue<<<dim3(1), dim3(1024), 0, stream>>>(statebuf, inputs, outputs, w_out, out);
}

// Round 6
// 7631.988 us; speedup vs baseline: 3.9053x; 3.9053x over previous
//
#include <hip/hip_runtime.h>

// Reservoir forward, R6: epoch-tagged IF exchange (R4 protocol) at 128 wgs,
// 512 thr/wg, 2 rows/wave. float4 LDS reads, paired 6-shuffle reduction.
// Lesson R5: agent-scope atomics always go to the Infinity Cache (sc0 sc1) --
// XCD placement is irrelevant for them; optimize width and the LDS pipe instead.

typedef unsigned long long u64;

#define NRES 2048
#define NIN  64
#define NOUT 16
#define TT   4096
#define GWG  128           // workgroups
#define BTH  512           // threads per wg (8 waves)
#define ROWS_PER_WG 16     // NRES / GWG, 2 rows per wave
#define NJ 8               // float4 blocks per lane (32 cols)

__global__ void init_ws(u64* statebuf) {
    int i = blockIdx.x * blockDim.x + threadIdx.x;
    if (i < NRES)            statebuf[i] = 0ull;                   // buf0: epoch 0, value 0
    else if (i < 2 * NRES)   statebuf[i] = 0xFFFFFFFF00000000ull;  // buf1: invalid epoch
}

__launch_bounds__(BTH, 2)   // 2 waves/SIMD min -> VGPR cap 256 (W fits in regs)
__global__ void reservoir_run(const float* __restrict__ inputs,
                              const float* __restrict__ outputs,
                              const float* __restrict__ noise,
                              const float* __restrict__ w,
                              const float* __restrict__ w_in,
                              const float* __restrict__ w_feedb,
                              u64* statebuf)
{
    const int wg   = blockIdx.x;      // 0..127
    const int tid  = threadIdx.x;     // 0..511
    const int wave = tid >> 6;        // 0..7
    const int lane = tid & 63;
    const int row0 = wg * ROWS_PER_WG + wave * 2;   // wave owns rows row0, row0+1

    // ---- W rows into VGPRs: 2 rows x 8 float4 = 64 regs/thread ----
    const float4* wr0 = (const float4*)(w + (size_t)(row0 + 0) * NRES);
    const float4* wr1 = (const float4*)(w + (size_t)(row0 + 1) * NRES);
    float4 wv0[NJ], wv1[NJ];
#pragma unroll
    for (int j = 0; j < NJ; ++j) {
        wv0[j] = wr0[64 * j + lane];
        wv1[j] = wr1[64 * j + lane];
    }
    // pin: block rematerialization (R3's failure mode)
#pragma unroll
    for (int j = 0; j < NJ; ++j) {
        asm volatile("" : "+v"(wv0[j].x), "+v"(wv0[j].y), "+v"(wv0[j].z), "+v"(wv0[j].w));
        asm volatile("" : "+v"(wv1[j].x), "+v"(wv1[j].y), "+v"(wv1[j].z), "+v"(wv1[j].w));
    }
    const float wi0 = w_in[(row0 + 0) * NIN + lane];
    const float wi1 = w_in[(row0 + 1) * NIN + lane];
    const float wf0 = (lane < NOUT) ? w_feedb[(row0 + 0) * NOUT + lane] : 0.0f;
    const float wf1 = (lane < NOUT) ? w_feedb[(row0 + 1) * NOUT + lane] : 0.0f;

    __shared__ float s_state[2][NRES];   // 16 KB parity double buffer

    // software-pipelined externals
    float inp_c = inputs[1 * NIN + lane];
    float po_c  = (lane < NOUT) ? outputs[0 * NOUT + lane] : 0.0f;
    float nz_c  = (lane < 2) ? noise[(size_t)1 * NRES + row0 + lane] : 0.0f;

    for (int t = 1; t < TT; ++t) {
        const u64* sbuf = statebuf + ((t - 1) & 1) * NRES;
        u64*       dbuf = statebuf + (t & 1) * NRES;
        float*     sl   = s_state[(t - 1) & 1];
        const unsigned want = (unsigned)(t - 1);

        float a0 = fmaf(wf0, po_c, wi0 * inp_c);
        float a1 = fmaf(wf1, po_c, wi1 * inp_c);
        const float nz = nz_c;

        // ---- poll-stage state(t-1): 4 u64 per thread, all loads in flight ----
        u64 p0 = __hip_atomic_load(&sbuf[tid],        __ATOMIC_RELAXED, __HIP_MEMORY_SCOPE_AGENT);
        u64 p1 = __hip_atomic_load(&sbuf[tid +  512], __ATOMIC_RELAXED, __HIP_MEMORY_SCOPE_AGENT);
        u64 p2 = __hip_atomic_load(&sbuf[tid + 1024], __ATOMIC_RELAXED, __HIP_MEMORY_SCOPE_AGENT);
        u64 p3 = __hip_atomic_load(&sbuf[tid + 1536], __ATOMIC_RELAXED, __HIP_MEMORY_SCOPE_AGENT);
        while ((unsigned)(p0 >> 32) != want)
            p0 = __hip_atomic_load(&sbuf[tid],        __ATOMIC_RELAXED, __HIP_MEMORY_SCOPE_AGENT);
        while ((unsigned)(p1 >> 32) != want)
            p1 = __hip_atomic_load(&sbuf[tid +  512], __ATOMIC_RELAXED, __HIP_MEMORY_SCOPE_AGENT);
        while ((unsigned)(p2 >> 32) != want)
            p2 = __hip_atomic_load(&sbuf[tid + 1024], __ATOMIC_RELAXED, __HIP_MEMORY_SCOPE_AGENT);
        while ((unsigned)(p3 >> 32) != want)
            p3 = __hip_atomic_load(&sbuf[tid + 1536], __ATOMIC_RELAXED, __HIP_MEMORY_SCOPE_AGENT);
        sl[tid]        = __uint_as_float((unsigned)p0);
        sl[tid +  512] = __uint_as_float((unsigned)p1);
        sl[tid + 1024] = __uint_as_float((unsigned)p2);
        sl[tid + 1536] = __uint_as_float((unsigned)p3);
        __syncthreads();

        // prefetch next step's externals (hide under FMA phase)
        if (t + 1 < TT) {
            inp_c = inputs[(t + 1) * NIN + lane];
            po_c  = (lane < NOUT) ? outputs[t * NOUT + lane] : 0.0f;
            nz_c  = (lane < 2) ? noise[(size_t)(t + 1) * NRES + row0 + lane] : 0.0f;
        }

        // ---- 2 row dot-products, float4 LDS reads (ds_read_b128) ----
        const float4* s4 = (const float4*)sl;
#pragma unroll
        for (int j = 0; j < NJ; ++j) {
            float4 sv = s4[64 * j + lane];
            a0 = fmaf(wv0[j].x, sv.x, a0); a0 = fmaf(wv0[j].y, sv.y, a0);
            a0 = fmaf(wv0[j].z, sv.z, a0); a0 = fmaf(wv0[j].w, sv.w, a0);
            a1 = fmaf(wv1[j].x, sv.x, a1); a1 = fmaf(wv1[j].y, sv.y, a1);
            a1 = fmaf(wv1[j].z, sv.z, a1); a1 = fmaf(wv1[j].w, sv.w, a1);
        }

        // ---- paired reduction: 6 shuffles for both rows ----
        // even lanes carry a0-chain, odd lanes carry a1-chain
        float c = (lane & 1) ? a1 : a0;
        float d = (lane & 1) ? a0 : a1;
        c += __shfl_xor(d, 1, 64);
#pragma unroll
        for (int off = 2; off <= 32; off <<= 1) c += __shfl_xor(c, off, 64);
        // lane 0: full a0 sum; lane 1: full a1 sum

        float ns = tanhf(c) + nz;      // all lanes compute; only 0,1 used
        if (lane < 2) {
            u64 pk = ((u64)(unsigned)t << 32) | (u64)__float_as_uint(ns);
            __hip_atomic_store(&dbuf[row0 + lane], pk, __ATOMIC_RELAXED,
                               __HIP_MEMORY_SCOPE_AGENT);
        }
    }
}

__global__ void epilogue(const u64* __restrict__ statebuf,
                         const float* __restrict__ inputs,
                         const float* __restrict__ outputs,
                         const float* __restrict__ w_out,
                         float* __restrict__ out)
{
    const u64* sb = statebuf + ((TT - 1) & 1) * NRES;   // state(4095) in buf 1
    const int tid  = threadIdx.x;   // 1024 threads = 16 waves
    const int wave = tid >> 6;
    const int lane = tid & 63;

    float acc = 0.0f;
#pragma unroll
    for (int k = 0; k < NRES / 64; ++k) {
        int r = lane + 64 * k;
        acc = fmaf(__uint_as_float((unsigned)sb[r]), w_out[r * NOUT + wave], acc);
    }
#pragma unroll
    for (int off = 32; off; off >>= 1) acc += __shfl_xor(acc, off, 64);
    if (lane == 0) out[wave] = acc;

    for (int i = tid; i < NRES; i += 1024)
        out[NOUT + i] = __uint_as_float((unsigned)sb[i]);
    if (tid < NIN)  out[NOUT + NRES + tid]       = inputs[(TT - 1) * NIN + tid];
    if (tid < NOUT) out[NOUT + NRES + NIN + tid] = outputs[(TT - 2) * NOUT + tid];
}

extern "C" void kernel_launch(void* const* d_in, const int* in_sizes, int n_in,
                              void* d_out, int out_size, void* d_ws, size_t ws_size,
                              hipStream_t stream) {
    const float* inputs  = (const float*)d_in[0];   // (4096, 64)
    const float* outputs = (const float*)d_in[1];   // (4096, 16)
    const float* noise   = (const float*)d_in[2];   // (4096, 2048)
    const float* w       = (const float*)d_in[3];   // (2048, 2048)
    const float* w_in    = (const float*)d_in[4];   // (2048, 64)
    const float* w_feedb = (const float*)d_in[5];   // (2048, 16)
    const float* w_out   = (const float*)d_in[6];   // (2048, 16)
    float* out = (float*)d_out;                     // 16 + 2128 floats

    u64* statebuf = (u64*)d_ws;                     // 2 * 2048 u64 = 32 KB

    init_ws<<<dim3(8), dim3(512), 0, stream>>>(statebuf);
    reservoir_run<<<dim3(GWG), dim3(BTH), 0, stream>>>(inputs, outputs, noise,
                                                       w, w_in, w_feedb, statebuf);
    epilogue<<<dim3(1), dim3(1024), 0, stream>>>(statebuf, inputs, outputs, w_out, out);
}